// Round 7
// baseline (3856.634 us; speedup 1.0000x reference)
//
#include <hip/hip_runtime.h>
#include <math.h>

#define NN 8192
#define DD 2048
#define KK 256
#define NB 256    // persistent blocks (1 per CU)
#define RPB 8     // G rows owned per block
#define POISON 0xFFFFFFFFu

// ---------- block reduce (256 threads, wave=64) — legacy kernels ----------
__device__ __forceinline__ float blockReduceSum(float val, float* sdata) {
    for (int off = 32; off > 0; off >>= 1)
        val += __shfl_down(val, off, 64);
    int wid = threadIdx.x >> 6;
    int lane = threadIdx.x & 63;
    __syncthreads();
    if (lane == 0) sdata[wid] = val;
    __syncthreads();
    return sdata[0] + sdata[1] + sdata[2] + sdata[3];
}

// ---------- agent-scope (device-coherent) accessors ----------
__device__ __forceinline__ float agload(const float* p) {
    return __hip_atomic_load(p, __ATOMIC_RELAXED, __HIP_MEMORY_SCOPE_AGENT);
}
__device__ __forceinline__ void agstore(float* p, float v) {
    __hip_atomic_store(p, v, __ATOMIC_RELAXED, __HIP_MEMORY_SCOPE_AGENT);
}
__device__ __forceinline__ unsigned agloadu(const unsigned* p) {
    return __hip_atomic_load(p, __ATOMIC_RELAXED, __HIP_MEMORY_SCOPE_AGENT);
}

// ---------- V0 [D][K] -> V0T [K][D] ----------
__global__ void ktranspose(const float* __restrict__ V0, float* __restrict__ V0T) {
    __shared__ float tile[32][33];
    int bx = blockIdx.x;
    int by = blockIdx.y;
    int tx = threadIdx.x % 32;
    int ty = threadIdx.x / 32;
    for (int r = ty; r < 32; r += 8)
        tile[r][tx] = V0[(size_t)(bx * 32 + r) * KK + by * 32 + tx];
    __syncthreads();
    for (int r = ty; r < 32; r += 8)
        V0T[(size_t)(by * 32 + r) * DD + bx * 32 + tx] = tile[tx][r];
}

// ---------- d0[k] = ||V0[:,k]|| ----------
__global__ void kd0(const float* __restrict__ V0T, float* __restrict__ d0) {
    __shared__ float sdata[4];
    int k = blockIdx.x;
    float acc = 0.f;
    for (int j = threadIdx.x; j < DD; j += 256) {
        float v = V0T[(size_t)k * DD + j];
        acc += v * v;
    }
    float s = blockReduceSum(acc, sdata);
    if (threadIdx.x == 0) d0[k] = sqrtf(s);
}

// ---------- G = x^T x, triangle tiles + inline mirror ----------
__global__ void ksyrk(const float* __restrict__ x, float* __restrict__ G) {
    __shared__ float As[32][68];
    __shared__ float Bs[32][68];
    int t = blockIdx.x;
    int bj = (int)((sqrtf(8.0f * (float)t + 1.0f) - 1.0f) * 0.5f);
    while ((bj + 1) * (bj + 2) / 2 <= t) ++bj;
    while (bj * (bj + 1) / 2 > t) --bj;
    int bi = t - bj * (bj + 1) / 2;
    int a0 = bi * 64, b0 = bj * 64;
    int tid = threadIdx.x;
    int al = tid % 64;
    int nl0 = tid / 64;
    int tr = tid / 16, tc = tid % 16;
    float acc[4][4] = {};
    for (int n0 = 0; n0 < NN; n0 += 32) {
        for (int pass = 0; pass < 8; ++pass) {
            int nl = nl0 + pass * 4;
            As[nl][al] = x[(size_t)(n0 + nl) * DD + a0 + al];
            Bs[nl][al] = x[(size_t)(n0 + nl) * DD + b0 + al];
        }
        __syncthreads();
        for (int kk2 = 0; kk2 < 32; ++kk2) {
            float4 a4 = *(const float4*)&As[kk2][tr * 4];
            float4 b4 = *(const float4*)&Bs[kk2][tc * 4];
            float a[4] = {a4.x, a4.y, a4.z, a4.w};
            float b[4] = {b4.x, b4.y, b4.z, b4.w};
            for (int i = 0; i < 4; ++i)
                for (int j = 0; j < 4; ++j)
                    acc[i][j] += a[i] * b[j];
        }
        __syncthreads();
    }
    for (int i = 0; i < 4; ++i) {
        float4 o = make_float4(acc[i][0], acc[i][1], acc[i][2], acc[i][3]);
        *(float4*)&G[(size_t)(a0 + tr * 4 + i) * DD + b0 + tc * 4] = o;
    }
    if (bi != bj) {
        for (int i = 0; i < 4; ++i)
            for (int j = 0; j < 4; ++j)
                G[(size_t)(b0 + tc * 4 + j) * DD + a0 + tr * 4 + i] = acc[i][j];
    }
}

// ---------- legacy fallback kernels (used only if cooperative launch fails) ----------
__global__ void kmatvecG(const float* __restrict__ G, const float* __restrict__ v,
                         float* __restrict__ s) {
    __shared__ float vs[DD];
    int tid = threadIdx.x;
    for (int t2 = 0; t2 < 8; ++t2) vs[tid + t2 * 256] = v[tid + t2 * 256];
    __syncthreads();
    int wave = tid >> 6, lane = tid & 63;
    int row = blockIdx.x * 4 + wave;
    const float* Gr = G + (size_t)row * DD;
    float a = 0.f;
    for (int c = 0; c < 8; ++c) {
        int idx = lane * 4 + c * 256;
        float4 gq = *(const float4*)(Gr + idx);
        float4 vq = *(const float4*)(vs + idx);
        a += gq.x * vq.x + gq.y * vq.y + gq.z * vq.z + gq.w * vq.w;
    }
    for (int off = 32; off > 0; off >>= 1) a += __shfl_down(a, off, 64);
    if (lane == 0) s[row] = a;
}

__global__ void kstep1(const float* __restrict__ G, const float* __restrict__ V0T,
                       const float* __restrict__ d0, const float* __restrict__ s,
                       float* __restrict__ g, float* __restrict__ Vn, int k) {
    __shared__ float u[DD];
    __shared__ float sdata[4];
    __shared__ float sinv;
    int tid = threadIdx.x;
    const float* v = V0T + (size_t)k * DD;
    float cf = 0.5f / d0[k];
    float acc = 0.f;
    for (int t2 = 0; t2 < 8; ++t2) {
        int j = tid + t2 * 256;
        float uj = 0.5f * v[j] + cf * s[j];
        u[j] = uj;
        acc += uj * uj;
    }
    float n2 = blockReduceSum(acc, sdata);
    if (tid == 0) sinv = 1.0f / sqrtf(n2);
    __syncthreads();
    float inv = sinv;
    if (blockIdx.x == 0) {
        for (int t2 = 0; t2 < 8; ++t2) {
            int j = tid + t2 * 256;
            Vn[(size_t)k * DD + j] = u[j] * inv;
        }
    }
    int wave = tid >> 6, lane = tid & 63;
    int row = blockIdx.x * 4 + wave;
    const float* Gr = G + (size_t)row * DD;
    float a = 0.f;
    for (int c = 0; c < 8; ++c) {
        int idx = lane * 4 + c * 256;
        float4 gq = *(const float4*)(Gr + idx);
        float4 uq = *(const float4*)(u + idx);
        a += gq.x * uq.x + gq.y * uq.y + gq.z * uq.z + gq.w * uq.w;
    }
    for (int off = 32; off > 0; off >>= 1) a += __shfl_down(a, off, 64);
    if (lane == 0) g[row] = a * inv;
}

__global__ void kstep2(float* __restrict__ G, const float* __restrict__ V0T,
                       const float* __restrict__ Vn, const float* __restrict__ g,
                       float* __restrict__ s_next, int k, int knext) {
    __shared__ float vn_s[DD];
    __shared__ float h_s[DD];
    __shared__ float w_s[DD];
    __shared__ float sdata[4];
    int tid = threadIdx.x;
    float acc = 0.f;
    for (int t2 = 0; t2 < 8; ++t2) {
        int j = tid + t2 * 256;
        float vnj = Vn[(size_t)k * DD + j];
        float gj = g[j];
        vn_s[j] = vnj;
        h_s[j] = gj;
        w_s[j] = V0T[(size_t)knext * DD + j];
        acc += vnj * gj;
    }
    float c = blockReduceSum(acc, sdata);
    for (int t2 = 0; t2 < 8; ++t2) {
        int j = tid + t2 * 256;
        h_s[j] -= c * vn_s[j];
    }
    __syncthreads();
    int wave = tid >> 6, lane = tid & 63;
    int row = blockIdx.x * 4 + wave;
    float vni = vn_s[row], gi = g[row];
    float* Gr = G + (size_t)row * DD;
    float a = 0.f;
    for (int cc = 0; cc < 8; ++cc) {
        int idx = lane * 4 + cc * 256;
        float4 Gq = *(float4*)(Gr + idx);
        float4 hq = *(const float4*)(h_s + idx);
        float4 vq = *(const float4*)(vn_s + idx);
        float4 wq = *(const float4*)(w_s + idx);
        Gq.x = Gq.x - vni * hq.x - gi * vq.x;
        Gq.y = Gq.y - vni * hq.y - gi * vq.y;
        Gq.z = Gq.z - vni * hq.z - gi * vq.z;
        Gq.w = Gq.w - vni * hq.w - gi * vq.w;
        a += Gq.x * wq.x + Gq.y * wq.y + Gq.z * wq.z + Gq.w * wq.w;
        *(float4*)(Gr + idx) = Gq;
    }
    for (int off = 32; off > 0; off >>= 1) a += __shfl_down(a, off, 64);
    if (lane == 0) s_next[row] = a;
}

// ---------- persistent loop: barrier-free dataflow, G in registers ----------
// All cross-block buffers are per-iteration WRITE-ONCE slots pre-poisoned to
// 0xFFFFFFFF. The 8 scalar partials per (k, block) double as ready flags for
// that block's 16 g/w vector elements (producer drains vmcnt between data
// stores and flag stores). Consumers poll accbuf[k] until poison-free, then
// gather g/w. No grid barrier, no atomics; monotonic slots -> no ABA.
// Algorithm identical to kloop4/5 (passed, absmax 0.015625):
//   A1=vn.g A2=g.vk A3=vn.vk A4=w.w A5=w.g A6=w.vn A7=w.vk A8=g.g
//   c=A1, alpha=A2-A1*A3, beta=A3
//   |s|^2 = A4 + a^2 + b^2*A8 - 2a*A6 - 2b*A5 + 2ab*A1 ; vk.s = A7 - a*A3 - b*A2
//   n2 = 0.25*d0^2 + cf*(vk.s) + cf^2*|s|^2 ; inv = 1/sqrt(n2)
//   u = 0.5 vk + cf*(w - alpha*vnp - beta*g) ; vn_k = u*inv
//   sweep: G_r -= vnp[r]*g + (g[r]-c*vnp[r])*vnp ; g'[r]=G_r.vn_k ; w'[r]=G_r.v_{k+1}
__global__ void __launch_bounds__(1024, 4) kloop6(
    float* __restrict__ G, const float* __restrict__ V0T,
    const float* __restrict__ d0v, float* __restrict__ Vn,
    float* __restrict__ gbufK, float* __restrict__ wbufK,
    float* __restrict__ accbuf) {
    __shared__ float vbuf[2][DD];   // vn ping-pong
    __shared__ float gs[DD];        // g_{k-1} gathered
    __shared__ float vx[DD];        // v_{k+1}
    __shared__ float scal[8];
    __shared__ float partg[16], partw[16];

    const int tid = threadIdx.x;
    const int b = blockIdx.x;
    const int wave = tid >> 6, lane = tid & 63;
    const int rowi = wave >> 1;
    const int half = wave & 1;
    const int row = b * RPB + rowi;
    const int d0i = tid, d1i = tid + 1024;
    const int ib = half * 1024 + lane * 4;
    const float* Gr = G + (size_t)row * DD;

    // ---- load G slab into registers (64 KB/block = 16 floats/thread) ----
    float4 Gq[4];
    #pragma unroll
    for (int c = 0; c < 4; ++c) Gq[c] = *(const float4*)(Gr + ib + c * 256);

    // ---- prologue: w0 = G0 v0 ; write slot 0 (data, vmcnt, flags) ----
    vbuf[0][d0i] = 0.f;
    vbuf[0][d1i] = 0.f;
    vx[d0i] = V0T[d0i];
    vx[d1i] = V0T[d1i];
    __syncthreads();
    {
        float aw = 0.f;
        #pragma unroll
        for (int c = 0; c < 4; ++c) {
            float4 xq = *(const float4*)(vx + ib + c * 256);
            aw += Gq[c].x * xq.x + Gq[c].y * xq.y + Gq[c].z * xq.z + Gq[c].w * xq.w;
        }
        for (int off = 32; off > 0; off >>= 1) aw += __shfl_down(aw, off, 64);
        if (lane == 0) partw[wave] = aw;
    }
    __syncthreads();
    if (tid < RPB) {
        int rg = b * RPB + tid;
        agstore(&wbufK[rg], partw[2 * tid] + partw[2 * tid + 1]);   // slot 0
        agstore(&gbufK[rg], 0.f);                                   // g_0 = 0
    }
    if (wave == 0) asm volatile("s_waitcnt vmcnt(0)" ::: "memory"); // data before flags
    if (tid < 8) {
        // slot-0 scalars with vnp=0, g=0: only A4=w.w, A7=w.v0 nonzero
        float sacc = 0.f;
        for (int r = 0; r < RPB; ++r) {
            int rg = b * RPB + r;
            float wr = partw[2 * r] + partw[2 * r + 1];
            if (tid == 3) sacc += wr * wr;
            else if (tid == 6) sacc += wr * vx[rg];
        }
        agstore(&accbuf[(size_t)tid * NB + b], sacc);
    }

    for (int k = 0; k < KK; ++k) {
        const int p = k & 1;
        const float* vnp = vbuf[p];
        float* vnew = vbuf[p ^ 1];
        const float* gsrc = gbufK + (size_t)k * DD;
        const float* wsrc = wbufK + (size_t)k * DD;
        const float* vk = V0T + (size_t)k * DD;

        // ---- poll scalar flags for slot k (waves 0..7), reduce to scal[] ----
        if (wave < 8) {
            const unsigned* ap = (const unsigned*)accbuf
                                 + (size_t)k * (8 * NB) + (size_t)wave * NB + lane * 4;
            unsigned x0, x1, x2, x3;
            for (;;) {
                x0 = agloadu(ap); x1 = agloadu(ap + 1);
                x2 = agloadu(ap + 2); x3 = agloadu(ap + 3);
                bool bad = (x0 == POISON) | (x1 == POISON) | (x2 == POISON) | (x3 == POISON);
                if (!__any(bad)) break;
                __builtin_amdgcn_s_sleep(1);
            }
            float sp = __uint_as_float(x0) + __uint_as_float(x1)
                     + __uint_as_float(x2) + __uint_as_float(x3);
            for (int off = 32; off > 0; off >>= 1) sp += __shfl_down(sp, off, 64);
            if (lane == 0) scal[wave] = sp;
        }
        __syncthreads();   // scal ready; slot-k vectors now guaranteed visible

        float A1 = scal[0], A2 = scal[1], A3 = scal[2], A4 = scal[3];
        float A5 = scal[4], A6 = scal[5], A7 = scal[6], A8 = scal[7];
        float d0k = d0v[k];
        float cf = 0.5f / d0k;
        float c_s = A1;
        float alpha = A2 - A1 * A3;
        float beta = A3;
        float ss = A4 + alpha * alpha + beta * beta * A8
                 - 2.f * alpha * A6 - 2.f * beta * A5 + 2.f * alpha * beta * A1;
        float vks = A7 - alpha * A3 - beta * A2;
        float n2 = 0.25f * d0k * d0k + cf * vks + cf * cf * ss;
        float inv = 1.0f / sqrtf(n2);

        // ---- gather g,w ; elementwise u -> vn_k ----
        float g0 = agload(&gsrc[d0i]), g1 = agload(&gsrc[d1i]);
        float w0 = agload(&wsrc[d0i]), w1 = agload(&wsrc[d1i]);
        float vk0 = vk[d0i], vk1 = vk[d1i];
        float vp0 = vnp[d0i], vp1 = vnp[d1i];
        gs[d0i] = g0;
        gs[d1i] = g1;
        float u0 = 0.5f * vk0 + cf * (w0 - alpha * vp0 - beta * g0);
        float u1 = 0.5f * vk1 + cf * (w1 - alpha * vp1 - beta * g1);
        vnew[d0i] = u0 * inv;
        vnew[d1i] = u1 * inv;
        if (k < KK - 1) {
            vx[d0i] = V0T[(size_t)(k + 1) * DD + d0i];
            vx[d1i] = V0T[(size_t)(k + 1) * DD + d1i];
        }
        __syncthreads();   // publish vnew, gs, vx

        if (tid < RPB) {   // distributed Vn row write (own slab elements)
            int rg = b * RPB + tid;
            agstore(&Vn[(size_t)k * DD + rg], vnew[rg]);
        }
        if (k == KK - 1) break;

        // ---- register sweep: deflate by pair (k-1), dot vs vn_k and v_{k+1} ----
        {
            float a_r = vnp[row];
            float g_r = gs[row];
            float b_r = g_r - c_s * a_r;
            float ag = 0.f, aw = 0.f;
            #pragma unroll
            for (int c = 0; c < 4; ++c) {
                int idx = ib + c * 256;
                float4 gq = *(const float4*)(gs + idx);
                float4 vq = *(const float4*)(vnp + idx);
                float4 nq = *(const float4*)(vnew + idx);
                float4 xq = *(const float4*)(vx + idx);
                Gq[c].x -= a_r * gq.x + b_r * vq.x;
                Gq[c].y -= a_r * gq.y + b_r * vq.y;
                Gq[c].z -= a_r * gq.z + b_r * vq.z;
                Gq[c].w -= a_r * gq.w + b_r * vq.w;
                ag += Gq[c].x * nq.x + Gq[c].y * nq.y + Gq[c].z * nq.z + Gq[c].w * nq.w;
                aw += Gq[c].x * xq.x + Gq[c].y * xq.y + Gq[c].z * xq.z + Gq[c].w * xq.w;
            }
            for (int off = 32; off > 0; off >>= 1) {
                ag += __shfl_down(ag, off, 64);
                aw += __shfl_down(aw, off, 64);
            }
            if (lane == 0) { partg[wave] = ag; partw[wave] = aw; }
        }
        __syncthreads();   // partg/partw ready for wave 0
        if (tid < RPB) {
            int rg = b * RPB + tid;
            agstore(&gbufK[(size_t)(k + 1) * DD + rg], partg[2 * tid] + partg[2 * tid + 1]);
            agstore(&wbufK[(size_t)(k + 1) * DD + rg], partw[2 * tid] + partw[2 * tid + 1]);
        }
        if (wave == 0) asm volatile("s_waitcnt vmcnt(0)" ::: "memory"); // data before flags
        if (tid < 8) {
            // producer partial for scalar index tid, summed over own 8 rows
            float sacc = 0.f;
            for (int r = 0; r < RPB; ++r) {
                int rg = b * RPB + r;
                float gr = partg[2 * r] + partg[2 * r + 1];
                float wr = partw[2 * r] + partw[2 * r + 1];
                float vnr = vnew[rg];
                float vxr = vx[rg];
                float t;
                switch (tid) {
                    case 0: t = vnr * gr; break;   // A1 = vn.g
                    case 1: t = gr * vxr; break;   // A2 = g.v
                    case 2: t = vnr * vxr; break;  // A3 = vn.v
                    case 3: t = wr * wr; break;    // A4 = w.w
                    case 4: t = wr * gr; break;    // A5 = w.g
                    case 5: t = wr * vnr; break;   // A6 = w.vn
                    case 6: t = wr * vxr; break;   // A7 = w.v
                    default: t = gr * gr; break;   // A8 = g.g
                }
                sacc += t;
            }
            agstore(&accbuf[(size_t)(k + 1) * (8 * NB) + (size_t)tid * NB + b], sacc);
        }
        // no barrier: next iteration's poll provides the ordering
    }
}

// ---------- out[N][K] = x . Vn^T ----------
__global__ void kout(const float* __restrict__ x, const float* __restrict__ Vn,
                     float* __restrict__ out) {
    __shared__ float As[32][68];
    __shared__ float Bs[32][68];
    int i0 = blockIdx.x * 64;
    int k0 = blockIdx.y * 64;
    int tid = threadIdx.x;
    int tr = tid / 16;
    int tc = tid % 16;
    float acc[4][4] = {};
    for (int j0 = 0; j0 < DD; j0 += 32) {
        int c = tid % 32;
        int r0 = tid / 32;
        for (int pass = 0; pass < 8; ++pass) {
            int rr = r0 + pass * 8;
            As[c][rr] = x[(size_t)(i0 + rr) * DD + j0 + c];
            Bs[c][rr] = Vn[(size_t)(k0 + rr) * DD + j0 + c];
        }
        __syncthreads();
        for (int kk = 0; kk < 32; ++kk) {
            float4 a4 = *(const float4*)&As[kk][tr * 4];
            float4 b4 = *(const float4*)&Bs[kk][tc * 4];
            float a[4] = {a4.x, a4.y, a4.z, a4.w};
            float b[4] = {b4.x, b4.y, b4.z, b4.w};
            for (int ar = 0; ar < 4; ++ar)
                for (int bc = 0; bc < 4; ++bc)
                    acc[ar][bc] += a[ar] * b[bc];
        }
        __syncthreads();
    }
    for (int ar = 0; ar < 4; ++ar) {
        float4 o = make_float4(acc[ar][0], acc[ar][1], acc[ar][2], acc[ar][3]);
        *(float4*)&out[(size_t)(i0 + tr * 4 + ar) * KK + k0 + tc * 4] = o;
    }
}

extern "C" void kernel_launch(void* const* d_in, const int* in_sizes, int n_in,
                              void* d_out, int out_size, void* d_ws, size_t ws_size,
                              hipStream_t stream) {
    const float* x  = (const float*)d_in[0];   // [N*D]
    const float* V0 = (const float*)d_in[1];   // [D*K]
    float* out = (float*)d_out;                // [N*K]

    float* G     = (float*)d_ws;                    // D*D
    float* V0T   = G + (size_t)DD * DD;             // K*D
    float* Vn    = V0T + (size_t)KK * DD;           // K*D
    float* gbufK = Vn + (size_t)KK * DD;            // K*D write-once slots
    float* wbufK = gbufK + (size_t)KK * DD;         // K*D write-once slots
    float* accbuf = wbufK + (size_t)KK * DD;        // K*8*NB flag/scalar slots
    float* d0    = accbuf + (size_t)KK * 8 * NB;    // K

    ktranspose<<<dim3(DD / 32, KK / 32), 256, 0, stream>>>(V0, V0T);
    kd0<<<KK, 256, 0, stream>>>(V0T, d0);
    ksyrk<<<528, 256, 0, stream>>>(x, G);

    // poison all dataflow slots (write-once; data validity = non-poison flags)
    hipMemsetAsync(gbufK, 0xFF, (size_t)KK * DD * sizeof(float), stream);
    hipMemsetAsync(wbufK, 0xFF, (size_t)KK * DD * sizeof(float), stream);
    hipMemsetAsync(accbuf, 0xFF, (size_t)KK * 8 * NB * sizeof(float), stream);

    void* kargs[] = {(void*)&G, (void*)&V0T, (void*)&d0, (void*)&Vn,
                     (void*)&gbufK, (void*)&wbufK, (void*)&accbuf};
    hipError_t cerr = hipLaunchCooperativeKernel(kloop6, dim3(NB), dim3(1024),
                                                 kargs, 0, stream);
    if (cerr != hipSuccess) {
        // fallback: original per-iteration launch loop (aliases into slot buffers)
        float* g = gbufK;
        float* sbuf = wbufK;
        kmatvecG<<<512, 256, 0, stream>>>(G, V0T, sbuf);
        for (int k = 0; k < KK; ++k) {
            float* s_cur = sbuf + (k & 1) * DD;
            float* s_nxt = sbuf + ((k + 1) & 1) * DD;
            kstep1<<<512, 256, 0, stream>>>(G, V0T, d0, s_cur, g, Vn, k);
            if (k < KK - 1)
                kstep2<<<512, 256, 0, stream>>>(G, V0T, Vn, g, s_nxt, k, k + 1);
        }
    }

    kout<<<dim3(NN / 64, KK / 64), 256, 0, stream>>>(x, Vn, out);
}

// Round 8
// 2951.828 us; speedup vs baseline: 1.3065x; 1.3065x over previous
//
#include <hip/hip_runtime.h>
#include <math.h>

#define NN 8192
#define DD 2048
#define KK 256
#define NB 256    // persistent blocks (1 per CU)
#define RPB 8     // G rows owned per block
#define NGRP 16   // barrier tree groups
#define GSZ 16    // blocks per group

// ---------- block reduce (256 threads, wave=64) — legacy kernels ----------
__device__ __forceinline__ float blockReduceSum(float val, float* sdata) {
    for (int off = 32; off > 0; off >>= 1)
        val += __shfl_down(val, off, 64);
    int wid = threadIdx.x >> 6;
    int lane = threadIdx.x & 63;
    __syncthreads();
    if (lane == 0) sdata[wid] = val;
    __syncthreads();
    return sdata[0] + sdata[1] + sdata[2] + sdata[3];
}

// ---------- agent-scope (device-coherent) accessors ----------
__device__ __forceinline__ float agload(const float* p) {
    return __hip_atomic_load(p, __ATOMIC_RELAXED, __HIP_MEMORY_SCOPE_AGENT);
}
__device__ __forceinline__ void agstore(float* p, float v) {
    __hip_atomic_store(p, v, __ATOMIC_RELAXED, __HIP_MEMORY_SCOPE_AGENT);
}

// ---------- per-slot dataflow barrier: tree arrival, flat release (kloop5-proven) ----------
// Monotonic counters in pre-zeroed per-iteration slots (no reset, no ABA).
// All cross-block-visible stores in the loop tail are issued by wave 0, so
// thread 0's own-wave vmcnt(0) drain covers them before the arrival bump.
__device__ __forceinline__ void dfsync(unsigned* grpc, unsigned* rootc, int slot, int b) {
    if (threadIdx.x == 0) {
        asm volatile("s_waitcnt vmcnt(0)" ::: "memory");
        int grp = b >> 4;
        unsigned* gw = grpc + ((size_t)slot * NGRP + grp) * 16;   // 64B apart
        unsigned* rw = rootc + (size_t)slot * 16;                 // 64B apart
        unsigned prev = __hip_atomic_fetch_add(gw, 1u, __ATOMIC_RELAXED, __HIP_MEMORY_SCOPE_AGENT);
        if (prev == GSZ - 1u)
            __hip_atomic_fetch_add(rw, 1u, __ATOMIC_RELAXED, __HIP_MEMORY_SCOPE_AGENT);
        while (__hip_atomic_load(rw, __ATOMIC_RELAXED, __HIP_MEMORY_SCOPE_AGENT) < (unsigned)NGRP)
            __builtin_amdgcn_s_sleep(2);
    }
    __syncthreads();
}

// ---------- V0 [D][K] -> V0T [K][D] ----------
__global__ void ktranspose(const float* __restrict__ V0, float* __restrict__ V0T) {
    __shared__ float tile[32][33];
    int bx = blockIdx.x;
    int by = blockIdx.y;
    int tx = threadIdx.x % 32;
    int ty = threadIdx.x / 32;
    for (int r = ty; r < 32; r += 8)
        tile[r][tx] = V0[(size_t)(bx * 32 + r) * KK + by * 32 + tx];
    __syncthreads();
    for (int r = ty; r < 32; r += 8)
        V0T[(size_t)(by * 32 + r) * DD + bx * 32 + tx] = tile[tx][r];
}

// ---------- d0[k] = ||V0[:,k]|| ----------
__global__ void kd0(const float* __restrict__ V0T, float* __restrict__ d0) {
    __shared__ float sdata[4];
    int k = blockIdx.x;
    float acc = 0.f;
    for (int j = threadIdx.x; j < DD; j += 256) {
        float v = V0T[(size_t)k * DD + j];
        acc += v * v;
    }
    float s = blockReduceSum(acc, sdata);
    if (threadIdx.x == 0) d0[k] = sqrtf(s);
}

// ---------- G = x^T x : 128x128 triangle tiles, 8x8 acc/thread, inline mirror ----------
__global__ void ksyrk128(const float* __restrict__ x, float* __restrict__ G) {
    __shared__ float As[16][132];
    __shared__ float Bs[16][132];
    int t = blockIdx.x;
    int bj = (int)((sqrtf(8.0f * (float)t + 1.0f) - 1.0f) * 0.5f);
    while ((bj + 1) * (bj + 2) / 2 <= t) ++bj;
    while (bj * (bj + 1) / 2 > t) --bj;
    int bi = t - bj * (bj + 1) / 2;
    int a0 = bi * 128, b0 = bj * 128;
    int tid = threadIdx.x;
    int ldr = tid >> 5;          // 0..7
    int ldc = (tid & 31) * 4;    // float col 0..124
    int tr = tid >> 4, tc = tid & 15;
    float acc[8][8] = {};
    for (int n0 = 0; n0 < NN; n0 += 16) {
        *(float4*)&As[ldr][ldc]     = *(const float4*)&x[(size_t)(n0 + ldr) * DD + a0 + ldc];
        *(float4*)&As[ldr + 8][ldc] = *(const float4*)&x[(size_t)(n0 + ldr + 8) * DD + a0 + ldc];
        *(float4*)&Bs[ldr][ldc]     = *(const float4*)&x[(size_t)(n0 + ldr) * DD + b0 + ldc];
        *(float4*)&Bs[ldr + 8][ldc] = *(const float4*)&x[(size_t)(n0 + ldr + 8) * DD + b0 + ldc];
        __syncthreads();
        for (int kk = 0; kk < 16; ++kk) {
            float4 alo = *(const float4*)&As[kk][tr * 4];
            float4 ahi = *(const float4*)&As[kk][64 + tr * 4];
            float4 blo = *(const float4*)&Bs[kk][tc * 4];
            float4 bhi = *(const float4*)&Bs[kk][64 + tc * 4];
            float a[8] = {alo.x, alo.y, alo.z, alo.w, ahi.x, ahi.y, ahi.z, ahi.w};
            float bb[8] = {blo.x, blo.y, blo.z, blo.w, bhi.x, bhi.y, bhi.z, bhi.w};
            #pragma unroll
            for (int i = 0; i < 8; ++i)
                #pragma unroll
                for (int j = 0; j < 8; ++j)
                    acc[i][j] += a[i] * bb[j];
        }
        __syncthreads();
    }
    #pragma unroll
    for (int i = 0; i < 8; ++i) {
        int lr = (i < 4) ? (tr * 4 + i) : (64 + tr * 4 + i - 4);
        size_t gr = (size_t)(a0 + lr) * DD;
        *(float4*)&G[gr + b0 + tc * 4] =
            make_float4(acc[i][0], acc[i][1], acc[i][2], acc[i][3]);
        *(float4*)&G[gr + b0 + 64 + tc * 4] =
            make_float4(acc[i][4], acc[i][5], acc[i][6], acc[i][7]);
    }
    if (bi != bj) {
        #pragma unroll
        for (int i = 0; i < 8; ++i) {
            int lr = (i < 4) ? (tr * 4 + i) : (64 + tr * 4 + i - 4);
            #pragma unroll
            for (int j = 0; j < 8; ++j) {
                int lc = (j < 4) ? (tc * 4 + j) : (64 + tc * 4 + j - 4);
                G[(size_t)(b0 + lc) * DD + a0 + lr] = acc[i][j];
            }
        }
    }
}

// ---------- legacy fallback kernels (used only if cooperative launch fails) ----------
__global__ void kmatvecG(const float* __restrict__ G, const float* __restrict__ v,
                         float* __restrict__ s) {
    __shared__ float vs[DD];
    int tid = threadIdx.x;
    for (int t2 = 0; t2 < 8; ++t2) vs[tid + t2 * 256] = v[tid + t2 * 256];
    __syncthreads();
    int wave = tid >> 6, lane = tid & 63;
    int row = blockIdx.x * 4 + wave;
    const float* Gr = G + (size_t)row * DD;
    float a = 0.f;
    for (int c = 0; c < 8; ++c) {
        int idx = lane * 4 + c * 256;
        float4 gq = *(const float4*)(Gr + idx);
        float4 vq = *(const float4*)(vs + idx);
        a += gq.x * vq.x + gq.y * vq.y + gq.z * vq.z + gq.w * vq.w;
    }
    for (int off = 32; off > 0; off >>= 1) a += __shfl_down(a, off, 64);
    if (lane == 0) s[row] = a;
}

__global__ void kstep1(const float* __restrict__ G, const float* __restrict__ V0T,
                       const float* __restrict__ d0, const float* __restrict__ s,
                       float* __restrict__ g, float* __restrict__ Vn, int k) {
    __shared__ float u[DD];
    __shared__ float sdata[4];
    __shared__ float sinv;
    int tid = threadIdx.x;
    const float* v = V0T + (size_t)k * DD;
    float cf = 0.5f / d0[k];
    float acc = 0.f;
    for (int t2 = 0; t2 < 8; ++t2) {
        int j = tid + t2 * 256;
        float uj = 0.5f * v[j] + cf * s[j];
        u[j] = uj;
        acc += uj * uj;
    }
    float n2 = blockReduceSum(acc, sdata);
    if (tid == 0) sinv = 1.0f / sqrtf(n2);
    __syncthreads();
    float inv = sinv;
    if (blockIdx.x == 0) {
        for (int t2 = 0; t2 < 8; ++t2) {
            int j = tid + t2 * 256;
            Vn[(size_t)k * DD + j] = u[j] * inv;
        }
    }
    int wave = tid >> 6, lane = tid & 63;
    int row = blockIdx.x * 4 + wave;
    const float* Gr = G + (size_t)row * DD;
    float a = 0.f;
    for (int c = 0; c < 8; ++c) {
        int idx = lane * 4 + c * 256;
        float4 gq = *(const float4*)(Gr + idx);
        float4 uq = *(const float4*)(u + idx);
        a += gq.x * uq.x + gq.y * uq.y + gq.z * uq.z + gq.w * uq.w;
    }
    for (int off = 32; off > 0; off >>= 1) a += __shfl_down(a, off, 64);
    if (lane == 0) g[row] = a * inv;
}

__global__ void kstep2(float* __restrict__ G, const float* __restrict__ V0T,
                       const float* __restrict__ Vn, const float* __restrict__ g,
                       float* __restrict__ s_next, int k, int knext) {
    __shared__ float vn_s[DD];
    __shared__ float h_s[DD];
    __shared__ float w_s[DD];
    __shared__ float sdata[4];
    int tid = threadIdx.x;
    float acc = 0.f;
    for (int t2 = 0; t2 < 8; ++t2) {
        int j = tid + t2 * 256;
        float vnj = Vn[(size_t)k * DD + j];
        float gj = g[j];
        vn_s[j] = vnj;
        h_s[j] = gj;
        w_s[j] = V0T[(size_t)knext * DD + j];
        acc += vnj * gj;
    }
    float c = blockReduceSum(acc, sdata);
    for (int t2 = 0; t2 < 8; ++t2) {
        int j = tid + t2 * 256;
        h_s[j] -= c * vn_s[j];
    }
    __syncthreads();
    int wave = tid >> 6, lane = tid & 63;
    int row = blockIdx.x * 4 + wave;
    float vni = vn_s[row], gi = g[row];
    float* Gr = G + (size_t)row * DD;
    float a = 0.f;
    for (int cc = 0; cc < 8; ++cc) {
        int idx = lane * 4 + cc * 256;
        float4 Gq = *(float4*)(Gr + idx);
        float4 hq = *(const float4*)(h_s + idx);
        float4 vq = *(const float4*)(vn_s + idx);
        float4 wq = *(const float4*)(w_s + idx);
        Gq.x = Gq.x - vni * hq.x - gi * vq.x;
        Gq.y = Gq.y - vni * hq.y - gi * vq.y;
        Gq.z = Gq.z - vni * hq.z - gi * vq.z;
        Gq.w = Gq.w - vni * hq.w - gi * vq.w;
        a += Gq.x * wq.x + Gq.y * wq.y + Gq.z * wq.z + Gq.w * wq.w;
        *(float4*)(Gr + idx) = Gq;
    }
    for (int off = 32; off > 0; off >>= 1) a += __shfl_down(a, off, 64);
    if (lane == 0) s_next[row] = a;
}

// ---------- persistent loop: register G, ONE barrier/iter, BLOCK-LOCAL scalars ----------
// Per iteration k (matrix in regs is G_{k-1}; vnp = vn_{k-1} in LDS; gathered
// g = G_{k-1} vn_{k-1} rows, w = G_{k-1} v_k rows — produced at end of k-1):
//   c = vnp.g ; gv = g.vk ; bv = vnp.vk      (block-local LDS/shfl reduces)
//   alpha = gv - c*bv ; beta = bv
//   u = 0.5 vk + cf*(w - alpha*vnp - beta*g) ; n2 = |u|^2 (local) ; vn_k = u/sqrt(n2)
//   sweep own rows: G_r -= vnp[r]*g + (g[r]-c*vnp[r])*vnp   [G_{k-1} -> G_k]
//                   g'[r] = G_k[r,:].vn_k ; w'[r] = G_k[r,:].v_{k+1}
//   store 16 row-values ; ONE dfsync(slot k+1).
// Same algebra as the validated kloop2 (round 2, passed); no L3 scalar exchange.
__global__ void __launch_bounds__(1024, 4) kloop7(
    float* __restrict__ G, const float* __restrict__ V0T,
    const float* __restrict__ d0v, float* __restrict__ Vn,
    float* __restrict__ gbuf, float* __restrict__ wbuf,
    unsigned* rootc, unsigned* grpc) {
    __shared__ float vbuf[2][DD];   // vn ping-pong
    __shared__ float gs[DD];        // gathered g (full vector)
    __shared__ float vx[DD];        // v_{k+1}
    __shared__ float red[3][16];
    __shared__ float redN[16];
    __shared__ float partg[16], partw[16];

    const int tid = threadIdx.x;
    const int b = blockIdx.x;
    const int wave = tid >> 6, lane = tid & 63;
    const int rowi = wave >> 1;
    const int half = wave & 1;
    const int row = b * RPB + rowi;
    const int d0i = tid, d1i = tid + 1024;
    const int ib = half * 1024 + lane * 4;
    const float* Gr = G + (size_t)row * DD;

    // ---- load G slab into registers (64 KB/block = 16 floats/thread) ----
    float4 Gq[4];
    #pragma unroll
    for (int c = 0; c < 4; ++c) Gq[c] = *(const float4*)(Gr + ib + c * 256);

    // ---- prologue: w0 = G0 v0 rows; g0 = 0 rows; slot 0 ----
    vbuf[0][d0i] = 0.f;
    vbuf[0][d1i] = 0.f;
    vx[d0i] = V0T[d0i];
    vx[d1i] = V0T[d1i];
    __syncthreads();
    {
        float aw = 0.f;
        #pragma unroll
        for (int c = 0; c < 4; ++c) {
            float4 xq = *(const float4*)(vx + ib + c * 256);
            aw += Gq[c].x * xq.x + Gq[c].y * xq.y + Gq[c].z * xq.z + Gq[c].w * xq.w;
        }
        for (int off = 32; off > 0; off >>= 1) aw += __shfl_down(aw, off, 64);
        if (lane == 0) partw[wave] = aw;
    }
    __syncthreads();
    if (tid < RPB) {
        int rg = b * RPB + tid;
        agstore(&wbuf[rg], partw[2 * tid] + partw[2 * tid + 1]);   // parity 0
        agstore(&gbuf[rg], 0.f);                                   // g_{-1} = 0
    }
    dfsync(grpc, rootc, 0, b);

    for (int k = 0; k < KK; ++k) {
        const int p = k & 1;
        const float* vnp = vbuf[p];
        float* vnew = vbuf[p ^ 1];
        const float* gsrc = gbuf + (size_t)p * DD;
        const float* wsrc = wbuf + (size_t)p * DD;
        float* gdst = gbuf + (size_t)(p ^ 1) * DD;
        float* wdst = wbuf + (size_t)(p ^ 1) * DD;
        const float* vk = V0T + (size_t)k * DD;

        // ---- gather g,w ; block-local fused dots: c = vnp.g, gv = g.vk, bv = vnp.vk ----
        float g0 = agload(&gsrc[d0i]), g1 = agload(&gsrc[d1i]);
        float w0 = agload(&wsrc[d0i]), w1 = agload(&wsrc[d1i]);
        float vk0 = vk[d0i], vk1 = vk[d1i];
        float vp0 = vnp[d0i], vp1 = vnp[d1i];
        gs[d0i] = g0;
        gs[d1i] = g1;
        float pc = vp0 * g0 + vp1 * g1;
        float pgv = g0 * vk0 + g1 * vk1;
        float pbv = vp0 * vk0 + vp1 * vk1;
        for (int off = 32; off > 0; off >>= 1) {
            pc += __shfl_down(pc, off, 64);
            pgv += __shfl_down(pgv, off, 64);
            pbv += __shfl_down(pbv, off, 64);
        }
        if (lane == 0) { red[0][wave] = pc; red[1][wave] = pgv; red[2][wave] = pbv; }
        __syncthreads();   // S1: red ready (gs also published)
        float c_s = 0.f, gv = 0.f, bv = 0.f;
        #pragma unroll
        for (int i = 0; i < 16; ++i) { c_s += red[0][i]; gv += red[1][i]; bv += red[2][i]; }
        float alpha = gv - c_s * bv;
        float beta = bv;
        float cf = 0.5f / d0v[k];

        // ---- u, n2 (local), vn_k ----
        float u0 = 0.5f * vk0 + cf * (w0 - alpha * vp0 - beta * g0);
        float u1 = 0.5f * vk1 + cf * (w1 - alpha * vp1 - beta * g1);
        float pn = u0 * u0 + u1 * u1;
        for (int off = 32; off > 0; off >>= 1) pn += __shfl_down(pn, off, 64);
        if (lane == 0) redN[wave] = pn;
        __syncthreads();   // S2: redN ready
        float n2 = 0.f;
        #pragma unroll
        for (int i = 0; i < 16; ++i) n2 += redN[i];
        float inv = 1.0f / sqrtf(n2);
        vnew[d0i] = u0 * inv;
        vnew[d1i] = u1 * inv;
        if (k < KK - 1) {
            vx[d0i] = V0T[(size_t)(k + 1) * DD + d0i];
            vx[d1i] = V0T[(size_t)(k + 1) * DD + d1i];
        }
        __syncthreads();   // S3: vnew, vx published

        if (tid < RPB) {   // distributed Vn row write (own slab elements)
            int rg = b * RPB + tid;
            agstore(&Vn[(size_t)k * DD + rg], vnew[rg]);
        }
        if (k == KK - 1) break;

        // ---- register sweep: deflate by pair (k-1), dot vs vn_k and v_{k+1} ----
        {
            float a_r = vnp[row];
            float g_r = gs[row];
            float b_r = g_r - c_s * a_r;
            float ag = 0.f, aw = 0.f;
            #pragma unroll
            for (int c = 0; c < 4; ++c) {
                int idx = ib + c * 256;
                float4 gq = *(const float4*)(gs + idx);
                float4 vq = *(const float4*)(vnp + idx);
                float4 nq = *(const float4*)(vnew + idx);
                float4 xq = *(const float4*)(vx + idx);
                Gq[c].x -= a_r * gq.x + b_r * vq.x;
                Gq[c].y -= a_r * gq.y + b_r * vq.y;
                Gq[c].z -= a_r * gq.z + b_r * vq.z;
                Gq[c].w -= a_r * gq.w + b_r * vq.w;
                ag += Gq[c].x * nq.x + Gq[c].y * nq.y + Gq[c].z * nq.z + Gq[c].w * nq.w;
                aw += Gq[c].x * xq.x + Gq[c].y * xq.y + Gq[c].z * xq.z + Gq[c].w * xq.w;
            }
            for (int off = 32; off > 0; off >>= 1) {
                ag += __shfl_down(ag, off, 64);
                aw += __shfl_down(aw, off, 64);
            }
            if (lane == 0) { partg[wave] = ag; partw[wave] = aw; }
        }
        __syncthreads();   // S4: partg/partw ready for wave 0
        if (tid < RPB) {
            int rg = b * RPB + tid;
            agstore(&gdst[rg], partg[2 * tid] + partg[2 * tid + 1]);
            agstore(&wdst[rg], partw[2 * tid] + partw[2 * tid + 1]);
        }
        dfsync(grpc, rootc, k + 1, b);   // wave-0 stores covered by its vmcnt drain
    }
}

// ---------- out[N][K] = x . Vn^T ----------
__global__ void kout(const float* __restrict__ x, const float* __restrict__ Vn,
                     float* __restrict__ out) {
    __shared__ float As[32][68];
    __shared__ float Bs[32][68];
    int i0 = blockIdx.x * 64;
    int k0 = blockIdx.y * 64;
    int tid = threadIdx.x;
    int tr = tid / 16;
    int tc = tid % 16;
    float acc[4][4] = {};
    for (int j0 = 0; j0 < DD; j0 += 32) {
        int c = tid % 32;
        int r0 = tid / 32;
        for (int pass = 0; pass < 8; ++pass) {
            int rr = r0 + pass * 8;
            As[c][rr] = x[(size_t)(i0 + rr) * DD + j0 + c];
            Bs[c][rr] = Vn[(size_t)(k0 + rr) * DD + j0 + c];
        }
        __syncthreads();
        for (int kk = 0; kk < 32; ++kk) {
            float4 a4 = *(const float4*)&As[kk][tr * 4];
            float4 b4 = *(const float4*)&Bs[kk][tc * 4];
            float a[4] = {a4.x, a4.y, a4.z, a4.w};
            float b[4] = {b4.x, b4.y, b4.z, b4.w};
            for (int ar = 0; ar < 4; ++ar)
                for (int bc = 0; bc < 4; ++bc)
                    acc[ar][bc] += a[ar] * b[bc];
        }
        __syncthreads();
    }
    for (int ar = 0; ar < 4; ++ar) {
        float4 o = make_float4(acc[ar][0], acc[ar][1], acc[ar][2], acc[ar][3]);
        *(float4*)&out[(size_t)(i0 + tr * 4 + ar) * KK + k0 + tc * 4] = o;
    }
}

extern "C" void kernel_launch(void* const* d_in, const int* in_sizes, int n_in,
                              void* d_out, int out_size, void* d_ws, size_t ws_size,
                              hipStream_t stream) {
    const float* x  = (const float*)d_in[0];   // [N*D]
    const float* V0 = (const float*)d_in[1];   // [D*K]
    float* out = (float*)d_out;                // [N*K]

    float* G    = (float*)d_ws;                 // D*D
    float* V0T  = G + (size_t)DD * DD;          // K*D
    float* Vn   = V0T + (size_t)KK * DD;        // K*D
    float* gbuf = Vn + (size_t)KK * DD;         // 2*D
    float* wbuf = gbuf + 2 * DD;                // 2*D
    float* d0   = wbuf + 2 * DD;                // K
    unsigned* rootc = (unsigned*)(d0 + KK);     // KK*16
    unsigned* grpc  = rootc + (size_t)KK * 16;  // KK*NGRP*16

    ktranspose<<<dim3(DD / 32, KK / 32), 256, 0, stream>>>(V0, V0T);
    kd0<<<KK, 256, 0, stream>>>(V0T, d0);
    ksyrk128<<<136, 256, 0, stream>>>(x, G);

    // zero per-slot barrier counters
    hipMemsetAsync(rootc, 0, ((size_t)KK * 16 + (size_t)KK * NGRP * 16) * sizeof(unsigned), stream);

    void* kargs[] = {(void*)&G, (void*)&V0T, (void*)&d0, (void*)&Vn,
                     (void*)&gbuf, (void*)&wbuf, (void*)&rootc, (void*)&grpc};
    hipError_t cerr = hipLaunchCooperativeKernel(kloop7, dim3(NB), dim3(1024),
                                                 kargs, 0, stream);
    if (cerr != hipSuccess) {
        // fallback: original per-iteration launch loop
        float* g = gbuf;
        float* sbuf = wbuf;   // fallback needs 2*D; wbuf provides it
        kmatvecG<<<512, 256, 0, stream>>>(G, V0T, sbuf);
        for (int k = 0; k < KK; ++k) {
            float* s_cur = sbuf + (k & 1) * DD;
            float* s_nxt = sbuf + ((k + 1) & 1) * DD;
            kstep1<<<512, 256, 0, stream>>>(G, V0T, d0, s_cur, g, Vn, k);
            if (k < KK - 1)
                kstep2<<<512, 256, 0, stream>>>(G, V0T, Vn, g, s_nxt, k, k + 1);
        }
    }

    kout<<<dim3(NN / 64, KK / 64), 256, 0, stream>>>(x, Vn, out);
}